// Round 4
// baseline (1250.289 us; speedup 1.0000x reference)
//
#include <hip/hip_runtime.h>

typedef unsigned short u16;
typedef __attribute__((ext_vector_type(8))) short bf16x8;   // 8 bf16 = 4 VGPRs (MFMA A/B frag)
typedef __attribute__((ext_vector_type(4))) float f32x4;    // MFMA C/D frag

// ---------- constants ----------
#define TSEQ 32      // LSTM time steps (reshape bug: seq runs over B)
#define NB   128     // LSTM batch
#define HDIM 400
#define KPAD 416     // 400 padded to 13*32 for MFMA K
#define G4   1600    // 4*H
#define TOK  4096    // 32*128 tokens
#define XGC  3200    // both dirs' gate cols
#define BPITCH 420   // LDS Whh pitch (shorts): 420*2B=840B -> 16 distinct banks across fr lanes

__device__ __forceinline__ float b2f(u16 u) {
  union { unsigned int i; float f; } v; v.i = ((unsigned int)u) << 16; return v.f;
}
__device__ __forceinline__ u16 f2b(float f) {
  union { float fl; unsigned int i; } v; v.fl = f;
  unsigned int r = v.i + 0x7fffu + ((v.i >> 16) & 1u);   // RNE
  return (u16)(r >> 16);
}
__device__ __forceinline__ float loadf(const void* p, long long i, int isbf) {
  return isbf ? b2f(((const u16*)p)[i]) : ((const float*)p)[i];
}
__device__ __forceinline__ u16 loadb(const void* p, long long i, int isbf) {
  return isbf ? ((const u16*)p)[i] : f2b(((const float*)p)[i]);
}
__device__ __forceinline__ float sigm_(float x) { return 1.0f / (1.0f + __expf(-x)); }
__device__ __forceinline__ float tanh_(float x) {
  float e = __expf(2.0f * x);
  return 1.0f - 2.0f / (e + 1.0f);   // exact limits at +-inf, no NaN
}

// ---------- input dtype sniffer ----------
__global__ __launch_bounds__(256) void sniff_kernel(const void* wemb, int* flag) {
  __shared__ int cf, cb;
  if (threadIdx.x == 0) { cf = 0; cb = 0; }
  __syncthreads();
  int okf = 0, okb = 0;
  for (int i = threadIdx.x; i < 8192; i += 256) {
    float f = ((const float*)wemb)[i];
    float af = fabsf(f);
    if (af > 1e-12f && af < 8.0f) okf++;
    u16 ub = ((const u16*)wemb)[i];
    float fb = b2f(ub); float ab = fabsf(fb);
    if (ub == 0 || (ab > 1e-12f && ab < 8.0f)) okb++;
  }
  atomicAdd(&cf, okf);
  atomicAdd(&cb, okb);
  __syncthreads();
  if (threadIdx.x == 0) flag[0] = (cb > cf) ? 1 : 0;
}

// ---------- embedding + faithful reshape ----------
// XP[t*128+n, d] = concat(word_emb, tag_emb)[flat row n*32+t]  (the view(L,B,-1) bug)
__global__ __launch_bounds__(256) void embed_kernel(
    const int* __restrict__ words, const int* __restrict__ tags,
    const void* __restrict__ wemb, const void* __restrict__ temb,
    const int* __restrict__ flag, u16* __restrict__ XP) {
  const int isbf = flag[0];
  int idx = blockIdx.x * 256 + threadIdx.x;      // 4096*400
  if (idx >= TOK * 400) return;
  int r = idx / 400, d = idx - r * 400;
  int t = r >> 7, n = r & 127;
  int m = n * 32 + t;                            // flat row of embeds (B,L,400)
  int b = m >> 7, l = m & 127;
  u16 v;
  if (d < 300) v = loadb(wemb, (long long)words[b * 128 + l] * 300 + d, isbf);
  else         v = loadb(temb, (long long)tags[b * 128 + l] * 100 + (d - 300), isbf);
  XP[(size_t)r * KPAD + d] = v;                  // pad cols [400,416) pre-zeroed by memset
}

// ---------- weight pre-arrangement ----------
// arranged gate row: ar = ctile*64 + type*16 + j  <->  orig row = type*400 + ctile*16 + j
__global__ __launch_bounds__(256) void prep_kernel(
    const void* wih0, const void* wih1, const void* wih2, const void* wih3,
    const void* whhA0, const void* whhA1, const void* whhA2, const void* whhA3,
    const void* bih0, const void* bih1, const void* bih2, const void* bih3,
    const void* bhh0, const void* bhh1, const void* bhh2, const void* bhh3,
    const void* w1, const void* b1, const void* w2, const void* b2,
    const int* __restrict__ flag,
    u16* __restrict__ W0a, u16* __restrict__ W1a, u16* __restrict__ WhhA,
    float* __restrict__ biasA, u16* __restrict__ W1ab, float* __restrict__ smallf) {
  const int isbf = flag[0];
  long long idx = (long long)blockIdx.x * 256 + threadIdx.x;
  const void* wihs[4] = {wih0, wih1, wih2, wih3};
  const void* whhs[4] = {whhA0, whhA1, whhA2, whhA3};
  const void* bihs[4] = {bih0, bih1, bih2, bih3};
  const void* bhhs[4] = {bhh0, bhh1, bhh2, bhh3};
  const long long c1 = 1331200LL, c2 = 3891200LL, c3 = 6553600LL, c4 = 6560000LL,
                  c5 = 6726400LL, c6 = 6726601LL;
  if (idx < c1) {                       // W0a: [2][1600][416]
    int j = (int)idx; int row = j / KPAD; int k = j - row * KPAD;
    int dir = row / G4; int ar = row - dir * G4;
    int ct = ar >> 6, rem = ar & 63, ty = rem >> 4, jj = rem & 15;
    int srow = ty * 400 + ct * 16 + jj;
    W0a[j] = (k < 400) ? loadb(wihs[dir], (long long)srow * 400 + k, isbf) : (u16)0;
  } else if (idx < c2) {                // W1a: [2][1600][800]
    int j = (int)(idx - c1); int row = j / 800; int k = j - row * 800;
    int dir = row / G4; int ar = row - dir * G4;
    int ct = ar >> 6, rem = ar & 63, ty = rem >> 4, jj = rem & 15;
    int srow = ty * 400 + ct * 16 + jj;
    W1a[j] = loadb(wihs[2 + dir], (long long)srow * 800 + k, isbf);
  } else if (idx < c3) {                // WhhA: [4][1600][416]
    int j = (int)(idx - c2); int row = j / KPAD; int k = j - row * KPAD;
    int dl = row / G4; int ar = row - dl * G4;
    int ct = ar >> 6, rem = ar & 63, ty = rem >> 4, jj = rem & 15;
    int srow = ty * 400 + ct * 16 + jj;
    WhhA[j] = (k < 400) ? loadb(whhs[dl], (long long)srow * 400 + k, isbf) : (u16)0;
  } else if (idx < c4) {                // biasA: [4][1600]
    int j = (int)(idx - c3); int dl = j / G4; int ar = j - dl * G4;
    int ct = ar >> 6, rem = ar & 63, ty = rem >> 4, jj = rem & 15;
    int srow = ty * 400 + ct * 16 + jj;
    biasA[j] = loadf(bihs[dl], srow, isbf) + loadf(bhhs[dl], srow, isbf);
  } else if (idx < c5) {                // W1ab: [208][800]
    int j = (int)(idx - c4); int row = j / 800; int k = j - row * 800;
    u16 v = 0;
    if (row < 100)      v = loadb(w1, (long long)row * 1600 + k, isbf);
    else if (row < 200) v = loadb(w1, (long long)(row - 100) * 1600 + 800 + k, isbf);
    W1ab[j] = v;
  } else if (idx < c6) {                // smallf: b1(100), w2(100), b2(1)
    int j = (int)(idx - c5);
    if (j < 100)       smallf[j] = loadf(b1, j, isbf);
    else if (j < 200)  smallf[j] = loadf(w2, j - 100, isbf);
    else               smallf[200] = loadf(b2, 0, isbf);
  }
}

// ---------- 128x128-tile bf16 GEMM: C[M][N] = A[M][K] @ B[N][K]^T (bf16 out) ----------
__global__ __launch_bounds__(256) void gemm_bt(
    const u16* __restrict__ A, const u16* __restrict__ B, u16* __restrict__ C,
    int M, int N, int K) {
  __shared__ u16 As[128 * 40];      // pitch 40 shorts = 80B
  __shared__ u16 Bs[128 * 40];
  int tid = threadIdx.x;
  int wave = tid >> 6, lane = tid & 63;
  int m0 = blockIdx.y << 7, n0 = blockIdx.x << 7;
  int wr = wave >> 1, wc = wave & 1;
  int arow = tid >> 2, aseg = tid & 3;
  const size_t aoff0 = (size_t)(m0 + arow) * K + aseg * 8;
  const size_t aoff1 = (size_t)(m0 + 64 + arow) * K + aseg * 8;
  const size_t boff0 = (size_t)(n0 + arow) * K + aseg * 8;
  const size_t boff1 = (size_t)(n0 + 64 + arow) * K + aseg * 8;
  float4 ra0 = *(const float4*)&A[aoff0];
  float4 ra1 = *(const float4*)&A[aoff1];
  float4 rb0 = *(const float4*)&B[boff0];
  float4 rb1 = *(const float4*)&B[boff1];
  f32x4 acc[4][4] = {};
  int fr = lane & 15, fkb = (lane >> 4) * 8;
  for (int k0 = 32;; k0 += 32) {
    __syncthreads();
    *(float4*)&As[arow * 40 + aseg * 8] = ra0;
    *(float4*)&As[(64 + arow) * 40 + aseg * 8] = ra1;
    *(float4*)&Bs[arow * 40 + aseg * 8] = rb0;
    *(float4*)&Bs[(64 + arow) * 40 + aseg * 8] = rb1;
    bool more = k0 < K;
    if (more) {
      ra0 = *(const float4*)&A[aoff0 + k0];
      ra1 = *(const float4*)&A[aoff1 + k0];
      rb0 = *(const float4*)&B[boff0 + k0];
      rb1 = *(const float4*)&B[boff1 + k0];
    }
    __syncthreads();
    bf16x8 af[4], bf[4];
#pragma unroll
    for (int i = 0; i < 4; i++) af[i] = *(const bf16x8*)&As[(wr * 64 + i * 16 + fr) * 40 + fkb];
#pragma unroll
    for (int i = 0; i < 4; i++) bf[i] = *(const bf16x8*)&Bs[(wc * 64 + i * 16 + fr) * 40 + fkb];
#pragma unroll
    for (int i = 0; i < 4; i++)
#pragma unroll
      for (int j = 0; j < 4; j++)
        acc[i][j] = __builtin_amdgcn_mfma_f32_16x16x32_bf16(af[i], bf[j], acc[i][j], 0, 0, 0);
    if (!more) break;
  }
  int rg = lane >> 4;
#pragma unroll
  for (int i = 0; i < 4; i++)
#pragma unroll
    for (int j = 0; j < 4; j++)
#pragma unroll
      for (int r = 0; r < 4; r++) {
        int row = m0 + wr * 64 + i * 16 + rg * 4 + r;
        int col = n0 + wc * 64 + j * 16 + fr;
        C[(size_t)row * N + col] = f2b(acc[i][j][r]);
      }
}

// ---------- device-scope group barrier (monotonic counter, agent scope) ----------
__device__ __forceinline__ void group_barrier(unsigned* cnt, int step1, int nblk) {
  __syncthreads();
  if (threadIdx.x == 0) {
    __threadfence();   // release: my h writes visible device-wide
    __hip_atomic_fetch_add(cnt, 1u, __ATOMIC_ACQ_REL, __HIP_MEMORY_SCOPE_AGENT);
    unsigned target = (unsigned)(nblk * step1);
    while (__hip_atomic_load(cnt, __ATOMIC_ACQUIRE, __HIP_MEMORY_SCOPE_AGENT) < target)
      __builtin_amdgcn_s_sleep(2);
  }
  __syncthreads();
  __threadfence();     // acquire: invalidate caches so fresh h is read
}

// ---------- persistent LSTM layer: 1 launch, 32 steps, grid(25,2,2)=100 blocks ----------
// Block (ctile, ntile, dir): rows n0..n0+64, gate cols ar0..ar0+64 (h-dims ctile*16..+16).
// Whh slice LDS-resident; A(h) loaded straight into MFMA frags; c in registers.
// Cross-block dep only within the 25-block (ntile,dir) group -> 4 independent barriers.
__global__ __launch_bounds__(256) void lstm_persist(
    const u16* __restrict__ xg,      // [4096][3200] precomputed x-part (no bias)
    const u16* __restrict__ Whh,     // [2][1600][416] arranged (this layer)
    const float* __restrict__ bias,  // [2][1600] arranged (this layer)
    u16* __restrict__ hA,            // [2][128][416] zeroed (step-0 input)
    u16* __restrict__ hB,            // [2][128][416] zeroed (pads stay 0)
    u16* __restrict__ h_cat,         // [4096][800]
    unsigned* __restrict__ bar) {    // [4] zeroed
  __shared__ u16 Bs[64 * BPITCH];    // 53760 B
  __shared__ float gs[64 * 68];      // 17408 B
  __shared__ float biasS[64];
  const int ctile = blockIdx.x, ntile = blockIdx.y, dir = blockIdx.z;
  const int n0 = ntile * 64, ar0 = ctile * 64;
  const int tid = threadIdx.x, lane = tid & 63, wave = tid >> 6;
  const int wr = wave >> 1, wc = wave & 1;
  const int fr = lane & 15, fkb = (lane >> 4) * 8;
  unsigned* cnt = bar + (dir * 2 + ntile);

  // stage Whh slice (64 rows x 416) into LDS, coalesced float4
  const u16* wbase = Whh + ((size_t)dir * G4 + ar0) * KPAD;
  for (int idx = tid; idx < 64 * 52; idx += 256) {
    int r = idx / 52, kk = (idx - r * 52) * 8;
    *(float4*)&Bs[r * BPITCH + kk] = *(const float4*)&wbase[(size_t)r * KPAD + kk];
  }
  if (tid < 64) biasS[tid] = bias[dir * G4 + ar0 + tid];
  __syncthreads();

  const u16* hin = hA;
  u16* hout = hB;
  float c_reg[4] = {0.f, 0.f, 0.f, 0.f};   // this thread's 4 cell states
  const int rg = lane >> 4;

  for (int s = 0; s < TSEQ; s++) {
    const int t = dir ? (31 - s) : s;
    // A fragments straight from global (L2-resident h), 26 x 16B pipelined loads
    const u16* hb = hin + (size_t)dir * NB * KPAD;
    bf16x8 areg[13][2];
#pragma unroll
    for (int k = 0; k < 13; k++)
#pragma unroll
      for (int i = 0; i < 2; i++)
        areg[k][i] = *(const bf16x8*)&hb[(size_t)(n0 + wr * 32 + i * 16 + fr) * KPAD + k * 32 + fkb];
    f32x4 acc[2][2] = {};
#pragma unroll
    for (int k = 0; k < 13; k++) {
      bf16x8 bf0 = *(const bf16x8*)&Bs[(wc * 32 + fr) * BPITCH + k * 32 + fkb];
      bf16x8 bf1 = *(const bf16x8*)&Bs[(wc * 32 + 16 + fr) * BPITCH + k * 32 + fkb];
      acc[0][0] = __builtin_amdgcn_mfma_f32_16x16x32_bf16(areg[k][0], bf0, acc[0][0], 0, 0, 0);
      acc[0][1] = __builtin_amdgcn_mfma_f32_16x16x32_bf16(areg[k][0], bf1, acc[0][1], 0, 0, 0);
      acc[1][0] = __builtin_amdgcn_mfma_f32_16x16x32_bf16(areg[k][1], bf0, acc[1][0], 0, 0, 0);
      acc[1][1] = __builtin_amdgcn_mfma_f32_16x16x32_bf16(areg[k][1], bf1, acc[1][1], 0, 0, 0);
    }
    // transpose gates through LDS for i/f/g/o gather
#pragma unroll
    for (int i = 0; i < 2; i++)
#pragma unroll
      for (int j = 0; j < 2; j++)
#pragma unroll
        for (int r = 0; r < 4; r++)
          gs[(wr * 32 + i * 16 + rg * 4 + r) * 68 + wc * 32 + j * 16 + fr] = acc[i][j][r];
    __syncthreads();
    // elementwise: 64 rows x 16 h-dims (fixed tid->item mapping keeps c in regs)
#pragma unroll
    for (int q = 0; q < 4; q++) {
      int it = tid + q * 256;
      int nl = it >> 4, j = it & 15;
      int n = n0 + nl;
      int row = t * 128 + n;
      size_t xb = (size_t)row * XGC + dir * G4 + ar0 + j;
      float gi = gs[nl * 68 + j]      + b2f(xg[xb])      + biasS[j];
      float gf = gs[nl * 68 + 16 + j] + b2f(xg[xb + 16]) + biasS[16 + j];
      float gg = gs[nl * 68 + 32 + j] + b2f(xg[xb + 32]) + biasS[32 + j];
      float go = gs[nl * 68 + 48 + j] + b2f(xg[xb + 48]) + biasS[48 + j];
      float c_new = sigm_(gf) * c_reg[q] + sigm_(gi) * tanh_(gg);
      float h_new = sigm_(go) * tanh_(c_new);
      c_reg[q] = c_new;
      int cidx = ctile * 16 + j;
      u16 hb16 = f2b(h_new);
      hout[((size_t)dir * NB + n) * KPAD + cidx] = hb16;
      h_cat[(size_t)row * 800 + dir * HDIM + cidx] = hb16;
    }
    // one barrier per step: releases hout, also guards gs reuse
    group_barrier(cnt, s + 1, 25);
    const u16* tmp = hin; hin = hout; hout = (u16*)tmp;
  }
}

// ---------- a/bm projection: [4096][200] = h1 @ W1ab^T, written permuted ----------
__global__ __launch_bounds__(256) void ab_gemm(
    const u16* __restrict__ h1, const u16* __restrict__ W1ab,
    const float* __restrict__ smallf, float* __restrict__ abuf, float* __restrict__ bbuf) {
  int lane = threadIdx.x & 63, wv = threadIdx.x >> 6;
  int mt = blockIdx.y * 4 + wv;
  int nt = blockIdx.x;
  int r0 = mt * 16, c0 = nt * 16;
  f32x4 acc = {};
  int fr = lane & 15, fk8 = (lane >> 4) * 8;
  for (int k0 = 0; k0 < 800; k0 += 32) {
    bf16x8 a = *(const bf16x8*)&h1[(size_t)(r0 + fr) * 800 + k0 + fk8];
    bf16x8 b = *(const bf16x8*)&W1ab[(size_t)(c0 + fr) * 800 + k0 + fk8];
    acc = __builtin_amdgcn_mfma_f32_16x16x32_bf16(a, b, acc, 0, 0, 0);
  }
  int c = c0 + fr;
  if (c < 200) {
#pragma unroll
    for (int r = 0; r < 4; r++) {
      int row = r0 + (lane >> 4) * 4 + r;
      int t = row >> 7, n = row & 127;
      int orow = n * 32 + t;
      float v = acc[r];
      if (c < 100) abuf[(size_t)orow * 100 + c] = v;
      else         bbuf[(size_t)orow * 100 + (c - 100)] = v + smallf[c - 100];
    }
  }
}

// ---------- fused pairwise MLP ----------
__global__ __launch_bounds__(256) void pairwise(
    const float* __restrict__ abuf, const float* __restrict__ bbuf,
    const float* __restrict__ smallf, const int* __restrict__ flag,
    void* __restrict__ outp) {
  __shared__ float aS[16 * 101];
  __shared__ float bS[16 * 101];
  __shared__ float w2S[104];
  int b = blockIdx.z, i0 = blockIdx.y * 16, j0 = blockIdx.x * 16;
  int tid = threadIdx.x;
  for (int idx = tid; idx < 1600; idx += 256) {
    int r = idx / 100, h = idx - r * 100;
    aS[r * 101 + h] = abuf[((size_t)(i0 + r) * 32 + b) * 100 + h];
    bS[r * 101 + h] = bbuf[((size_t)(j0 + r) * 32 + b) * 100 + h];
  }
  if (tid < 100) w2S[tid] = smallf[100 + tid];
  __syncthreads();
  float bias2 = smallf[200];
  int di = tid >> 4, dj = tid & 15;
  const float* ar = &aS[di * 101];
  const float* br = &bS[dj * 101];
  float s = 0.0f;
#pragma unroll 4
  for (int h = 0; h < 100; h++) s += w2S[h] * tanh_(ar[h] + br[h]);
  int i = i0 + di, j = j0 + dj;
  size_t pos = ((size_t)(i * 128 + j)) * 32 + b;
  float v = s + bias2;
  if (flag[0]) ((u16*)outp)[pos] = f2b(v);
  else         ((float*)outp)[pos] = v;
}

// ---------- host ----------
extern "C" void kernel_launch(void* const* d_in, const int* in_sizes, int n_in,
                              void* d_out, int out_size, void* d_ws, size_t ws_size,
                              hipStream_t stream) {
  (void)in_sizes; (void)n_in; (void)out_size; (void)ws_size;
  const int* words = (const int*)d_in[0];
  const int* tags  = (const int*)d_in[1];
  const void* wemb = d_in[4];
  const void* temb = d_in[5];
  const void* wih[4] = {d_in[6],  d_in[10], d_in[14], d_in[18]};
  const void* whh[4] = {d_in[7],  d_in[11], d_in[15], d_in[19]};
  const void* bih[4] = {d_in[8],  d_in[12], d_in[16], d_in[20]};
  const void* bhh[4] = {d_in[9],  d_in[13], d_in[17], d_in[21]};
  const void* w1 = d_in[22];
  const void* b1 = d_in[23];
  const void* w2 = d_in[24];
  const void* b2 = d_in[25];

  char* ws = (char*)d_ws;
  size_t off = 0;
  auto alloc = [&](size_t bytes) -> void* {
    void* p = ws + off; off = (off + bytes + 255) & ~(size_t)255; return p;
  };
  int*      flag  = (int*)     alloc(256);
  u16*      hstate= (u16*)     alloc((size_t)2 * 2 * NB * KPAD * 2);  // ping+pong, 416 KB
  unsigned* bar   = (unsigned*)alloc(256);                            // 4 group counters
  float*    smallf= (float*)   alloc(201 * 4);
  float*    abuf  = (float*)   alloc((size_t)TOK * 100 * 4);
  float*    bbuf  = (float*)   alloc((size_t)TOK * 100 * 4);
  u16*      hcat0 = (u16*)     alloc((size_t)TOK * 800 * 2);
  u16*      hcat1 = (u16*)     alloc((size_t)TOK * 800 * 2);
  u16*      XP    = (u16*)     alloc((size_t)TOK * KPAD * 2);
  u16*      xg    = (u16*)     alloc((size_t)TOK * XGC * 2);          // 26.2 MB
  u16*      W0a   = (u16*)     alloc((size_t)2 * G4 * KPAD * 2);
  u16*      W1a   = (u16*)     alloc((size_t)2 * G4 * 800 * 2);
  u16*      WhhA  = (u16*)     alloc((size_t)4 * G4 * KPAD * 2);
  float*    biasA = (float*)   alloc((size_t)4 * G4 * 4);
  u16*      W1ab  = (u16*)     alloc((size_t)208 * 800 * 2);

  const size_t stateBytes = (size_t)2 * 2 * NB * KPAD * 2;  // 425984, multiple of 256
  u16* h0 = hstate;
  u16* h1 = hstate + (size_t)2 * NB * KPAD;

  sniff_kernel<<<1, 256, 0, stream>>>(wemb, flag);
  hipMemsetAsync(XP, 0, (size_t)TOK * KPAD * 2, stream);     // zero K-pad cols
  prep_kernel<<<26276, 256, 0, stream>>>(
      wih[0], wih[1], wih[2], wih[3], whh[0], whh[1], whh[2], whh[3],
      bih[0], bih[1], bih[2], bih[3], bhh[0], bhh[1], bhh[2], bhh[3],
      w1, b1, w2, b2, flag, W0a, W1a, WhhA, biasA, W1ab, smallf);
  embed_kernel<<<6400, 256, 0, stream>>>(words, tags, wemb, temb, flag, XP);

  // layer 0: xg = XP @ W0a^T ; persistent recurrence
  gemm_bt<<<dim3(25, 32), 256, 0, stream>>>(XP, W0a, xg, TOK, XGC, KPAD);
  hipMemsetAsync(hstate, 0, stateBytes + 256, stream);       // h ping/pong + barrier counters
  lstm_persist<<<dim3(25, 2, 2), 256, 0, stream>>>(
      xg, WhhA, biasA, h0, h1, hcat0, bar);

  // layer 1: xg = hcat0 @ W1a^T ; persistent recurrence
  gemm_bt<<<dim3(25, 32), 256, 0, stream>>>(hcat0, W1a, xg, TOK, XGC, 800);
  hipMemsetAsync(hstate, 0, stateBytes + 256, stream);
  lstm_persist<<<dim3(25, 2, 2), 256, 0, stream>>>(
      xg, WhhA + (size_t)2 * G4 * KPAD, biasA + 2 * G4, h0, h1, hcat1, bar);

  ab_gemm<<<dim3(13, 64), 256, 0, stream>>>(hcat1, W1ab, smallf, abuf, bbuf);
  pairwise<<<dim3(8, 8, 32), 256, 0, stream>>>(abuf, bbuf, smallf, flag, d_out);
}

// Round 5
// 588.080 us; speedup vs baseline: 2.1261x; 2.1261x over previous
//
#include <hip/hip_runtime.h>

typedef unsigned short u16;
typedef __attribute__((ext_vector_type(8))) short bf16x8;   // 8 bf16 = 4 VGPRs (MFMA A/B frag)
typedef __attribute__((ext_vector_type(4))) float f32x4;    // MFMA C/D frag

// ---------- constants ----------
#define TSEQ 32      // LSTM time steps (reshape bug: seq runs over B)
#define NB   128     // LSTM batch
#define HDIM 400
#define KPAD 416     // 400 padded to 13*32 for MFMA K
#define G4   1600    // 4*H
#define TOK  4096    // 32*128 tokens
#define XGC  3200    // both dirs' gate cols
#define BPITCH 420   // LDS Whh pitch (shorts): 840B -> 16 distinct banks across fr lanes

__device__ __forceinline__ float b2f(u16 u) {
  union { unsigned int i; float f; } v; v.i = ((unsigned int)u) << 16; return v.f;
}
__device__ __forceinline__ u16 f2b(float f) {
  union { float fl; unsigned int i; } v; v.fl = f;
  unsigned int r = v.i + 0x7fffu + ((v.i >> 16) & 1u);   // RNE
  return (u16)(r >> 16);
}
__device__ __forceinline__ float loadf(const void* p, long long i, int isbf) {
  return isbf ? b2f(((const u16*)p)[i]) : ((const float*)p)[i];
}
__device__ __forceinline__ u16 loadb(const void* p, long long i, int isbf) {
  return isbf ? ((const u16*)p)[i] : f2b(((const float*)p)[i]);
}
__device__ __forceinline__ float sigm_(float x) { return 1.0f / (1.0f + __expf(-x)); }
__device__ __forceinline__ float tanh_(float x) {
  float e = __expf(2.0f * x);
  return 1.0f - 2.0f / (e + 1.0f);   // exact limits at +-inf, no NaN
}

// MALL-coherent (cross-XCD) primitives: sc0 sc1 = bypass/write-through L2. No fences.
__device__ __forceinline__ void load_h_frag(bf16x8* dst, const u16* p) {
  asm volatile("global_load_dwordx4 %0, %1, off sc0 sc1" : "=v"(*dst) : "v"(p));
}
__device__ __forceinline__ void store_h16(u16* p, unsigned v) {
  asm volatile("global_store_short %0, %1, off sc0 sc1" :: "v"(p), "v"(v) : "memory");
}
__device__ __forceinline__ unsigned poll_cnt(const unsigned* p) {
  unsigned v;
  asm volatile("global_load_dword %0, %1, off sc0 sc1\n\ts_waitcnt vmcnt(0)"
               : "=v"(v) : "v"(p) : "memory");
  return v;
}

// ---------- input dtype sniffer ----------
__global__ __launch_bounds__(256) void sniff_kernel(const void* wemb, int* flag) {
  __shared__ int cf, cb;
  if (threadIdx.x == 0) { cf = 0; cb = 0; }
  __syncthreads();
  int okf = 0, okb = 0;
  for (int i = threadIdx.x; i < 8192; i += 256) {
    float f = ((const float*)wemb)[i];
    float af = fabsf(f);
    if (af > 1e-12f && af < 8.0f) okf++;
    u16 ub = ((const u16*)wemb)[i];
    float fb = b2f(ub); float ab = fabsf(fb);
    if (ub == 0 || (ab > 1e-12f && ab < 8.0f)) okb++;
  }
  atomicAdd(&cf, okf);
  atomicAdd(&cb, okb);
  __syncthreads();
  if (threadIdx.x == 0) flag[0] = (cb > cf) ? 1 : 0;
}

// ---------- embedding + faithful reshape ----------
// XP[t*128+n, d] = concat(word_emb, tag_emb)[flat row n*32+t]  (the view(L,B,-1) bug)
__global__ __launch_bounds__(256) void embed_kernel(
    const int* __restrict__ words, const int* __restrict__ tags,
    const void* __restrict__ wemb, const void* __restrict__ temb,
    const int* __restrict__ flag, u16* __restrict__ XP) {
  const int isbf = flag[0];
  int idx = blockIdx.x * 256 + threadIdx.x;      // 4096*400
  if (idx >= TOK * 400) return;
  int r = idx / 400, d = idx - r * 400;
  int t = r >> 7, n = r & 127;
  int m = n * 32 + t;                            // flat row of embeds (B,L,400)
  int b = m >> 7, l = m & 127;
  u16 v;
  if (d < 300) v = loadb(wemb, (long long)words[b * 128 + l] * 300 + d, isbf);
  else         v = loadb(temb, (long long)tags[b * 128 + l] * 100 + (d - 300), isbf);
  XP[(size_t)r * KPAD + d] = v;                  // pad cols [400,416) pre-zeroed by memset
}

// ---------- weight pre-arrangement ----------
// arranged gate row: ar = ctile*64 + type*16 + j  <->  orig row = type*400 + ctile*16 + j
__global__ __launch_bounds__(256) void prep_kernel(
    const void* wih0, const void* wih1, const void* wih2, const void* wih3,
    const void* whhA0, const void* whhA1, const void* whhA2, const void* whhA3,
    const void* bih0, const void* bih1, const void* bih2, const void* bih3,
    const void* bhh0, const void* bhh1, const void* bhh2, const void* bhh3,
    const void* w1, const void* b1, const void* w2, const void* b2,
    const int* __restrict__ flag,
    u16* __restrict__ W0a, u16* __restrict__ W1a, u16* __restrict__ WhhA,
    float* __restrict__ biasA, u16* __restrict__ W1ab, float* __restrict__ smallf) {
  const int isbf = flag[0];
  long long idx = (long long)blockIdx.x * 256 + threadIdx.x;
  const void* wihs[4] = {wih0, wih1, wih2, wih3};
  const void* whhs[4] = {whhA0, whhA1, whhA2, whhA3};
  const void* bihs[4] = {bih0, bih1, bih2, bih3};
  const void* bhhs[4] = {bhh0, bhh1, bhh2, bhh3};
  const long long c1 = 1331200LL, c2 = 3891200LL, c3 = 6553600LL, c4 = 6560000LL,
                  c5 = 6726400LL, c6 = 6726601LL;
  if (idx < c1) {                       // W0a: [2][1600][416]
    int j = (int)idx; int row = j / KPAD; int k = j - row * KPAD;
    int dir = row / G4; int ar = row - dir * G4;
    int ct = ar >> 6, rem = ar & 63, ty = rem >> 4, jj = rem & 15;
    int srow = ty * 400 + ct * 16 + jj;
    W0a[j] = (k < 400) ? loadb(wihs[dir], (long long)srow * 400 + k, isbf) : (u16)0;
  } else if (idx < c2) {                // W1a: [2][1600][800]
    int j = (int)(idx - c1); int row = j / 800; int k = j - row * 800;
    int dir = row / G4; int ar = row - dir * G4;
    int ct = ar >> 6, rem = ar & 63, ty = rem >> 4, jj = rem & 15;
    int srow = ty * 400 + ct * 16 + jj;
    W1a[j] = loadb(wihs[2 + dir], (long long)srow * 800 + k, isbf);
  } else if (idx < c3) {                // WhhA: [4][1600][416]
    int j = (int)(idx - c2); int row = j / KPAD; int k = j - row * KPAD;
    int dl = row / G4; int ar = row - dl * G4;
    int ct = ar >> 6, rem = ar & 63, ty = rem >> 4, jj = rem & 15;
    int srow = ty * 400 + ct * 16 + jj;
    WhhA[j] = (k < 400) ? loadb(whhs[dl], (long long)srow * 400 + k, isbf) : (u16)0;
  } else if (idx < c4) {                // biasA: [4][1600]
    int j = (int)(idx - c3); int dl = j / G4; int ar = j - dl * G4;
    int ct = ar >> 6, rem = ar & 63, ty = rem >> 4, jj = rem & 15;
    int srow = ty * 400 + ct * 16 + jj;
    biasA[j] = loadf(bihs[dl], srow, isbf) + loadf(bhhs[dl], srow, isbf);
  } else if (idx < c5) {                // W1ab: [208][800]
    int j = (int)(idx - c4); int row = j / 800; int k = j - row * 800;
    u16 v = 0;
    if (row < 100)      v = loadb(w1, (long long)row * 1600 + k, isbf);
    else if (row < 200) v = loadb(w1, (long long)(row - 100) * 1600 + 800 + k, isbf);
    W1ab[j] = v;
  } else if (idx < c6) {                // smallf: b1(100), w2(100), b2(1)
    int j = (int)(idx - c5);
    if (j < 100)       smallf[j] = loadf(b1, j, isbf);
    else if (j < 200)  smallf[j] = loadf(w2, j - 100, isbf);
    else               smallf[200] = loadf(b2, 0, isbf);
  }
}

// ---------- 128x128-tile bf16 GEMM: C[M][N] = A[M][K] @ B[N][K]^T (bf16 out) ----------
__global__ __launch_bounds__(256) void gemm_bt(
    const u16* __restrict__ A, const u16* __restrict__ B, u16* __restrict__ C,
    int M, int N, int K) {
  __shared__ u16 As[128 * 40];      // pitch 40 shorts = 80B
  __shared__ u16 Bs[128 * 40];
  int tid = threadIdx.x;
  int wave = tid >> 6, lane = tid & 63;
  int m0 = blockIdx.y << 7, n0 = blockIdx.x << 7;
  int wr = wave >> 1, wc = wave & 1;
  int arow = tid >> 2, aseg = tid & 3;
  const size_t aoff0 = (size_t)(m0 + arow) * K + aseg * 8;
  const size_t aoff1 = (size_t)(m0 + 64 + arow) * K + aseg * 8;
  const size_t boff0 = (size_t)(n0 + arow) * K + aseg * 8;
  const size_t boff1 = (size_t)(n0 + 64 + arow) * K + aseg * 8;
  float4 ra0 = *(const float4*)&A[aoff0];
  float4 ra1 = *(const float4*)&A[aoff1];
  float4 rb0 = *(const float4*)&B[boff0];
  float4 rb1 = *(const float4*)&B[boff1];
  f32x4 acc[4][4] = {};
  int fr = lane & 15, fkb = (lane >> 4) * 8;
  for (int k0 = 32;; k0 += 32) {
    __syncthreads();
    *(float4*)&As[arow * 40 + aseg * 8] = ra0;
    *(float4*)&As[(64 + arow) * 40 + aseg * 8] = ra1;
    *(float4*)&Bs[arow * 40 + aseg * 8] = rb0;
    *(float4*)&Bs[(64 + arow) * 40 + aseg * 8] = rb1;
    bool more = k0 < K;
    if (more) {
      ra0 = *(const float4*)&A[aoff0 + k0];
      ra1 = *(const float4*)&A[aoff1 + k0];
      rb0 = *(const float4*)&B[boff0 + k0];
      rb1 = *(const float4*)&B[boff1 + k0];
    }
    __syncthreads();
    bf16x8 af[4], bf[4];
#pragma unroll
    for (int i = 0; i < 4; i++) af[i] = *(const bf16x8*)&As[(wr * 64 + i * 16 + fr) * 40 + fkb];
#pragma unroll
    for (int i = 0; i < 4; i++) bf[i] = *(const bf16x8*)&Bs[(wc * 64 + i * 16 + fr) * 40 + fkb];
#pragma unroll
    for (int i = 0; i < 4; i++)
#pragma unroll
      for (int j = 0; j < 4; j++)
        acc[i][j] = __builtin_amdgcn_mfma_f32_16x16x32_bf16(af[i], bf[j], acc[i][j], 0, 0, 0);
    if (!more) break;
  }
  int rg = lane >> 4;
#pragma unroll
  for (int i = 0; i < 4; i++)
#pragma unroll
    for (int j = 0; j < 4; j++)
#pragma unroll
      for (int r = 0; r < 4; r++) {
        int row = m0 + wr * 64 + i * 16 + rg * 4 + r;
        int col = n0 + wc * 64 + j * 16 + fr;
        C[(size_t)row * N + col] = f2b(acc[i][j][r]);
      }
}

// ---------- persistent LSTM layer: 1 launch, 32 steps, grid(25,2,2)=100 blocks ----------
// Block (ctile, ntile, dir): rows n0..n0+64, gate cols ar0..ar0+64 (h-dims ctile*16..+16).
// Whh slice LDS-resident; h exchanged via MALL-coherent sc0sc1 ops; c in registers.
// NO fences, NO acquire atomics -> per-XCD L2 stays warm (xg cached).
__global__ __launch_bounds__(256) void lstm_persist(
    const u16* __restrict__ xg,      // [4096][3200] precomputed x-part (no bias)
    const u16* __restrict__ Whh,     // [2][1600][416] arranged (this layer)
    const float* __restrict__ bias,  // [2][1600] arranged (this layer)
    u16* __restrict__ hA,            // [2][128][416] zeroed (step-0 input)
    u16* __restrict__ hB,            // [2][128][416] zeroed (pads stay 0)
    u16* __restrict__ h_cat,         // [4096][800]
    unsigned* __restrict__ bar) {    // 4 counters, 32B apart, zeroed
  __shared__ u16 Bs[64 * BPITCH];    // 53760 B
  __shared__ float gs[64 * 68];      // 17408 B
  __shared__ float biasS[64];
  const int ctile = blockIdx.x, ntile = blockIdx.y, dir = blockIdx.z;
  const int n0 = ntile * 64, ar0 = ctile * 64;
  const int tid = threadIdx.x, lane = tid & 63, wave = tid >> 6;
  const int wr = wave >> 1, wc = wave & 1;
  const int fr = lane & 15, fkb = (lane >> 4) * 8;
  unsigned* cnt = bar + (dir * 2 + ntile) * 8;   // 32B-padded counters

  // stage Whh slice (64 rows x 416) into LDS, coalesced float4
  const u16* wbase = Whh + ((size_t)dir * G4 + ar0) * KPAD;
  for (int idx = tid; idx < 64 * 52; idx += 256) {
    int r = idx / 52, kk = (idx - r * 52) * 8;
    *(float4*)&Bs[r * BPITCH + kk] = *(const float4*)&wbase[(size_t)r * KPAD + kk];
  }
  if (tid < 64) biasS[tid] = bias[dir * G4 + ar0 + tid];
  __syncthreads();

  const u16* hin = hA;
  u16* hout = hB;
  float c_reg[4] = {0.f, 0.f, 0.f, 0.f};   // this thread's 4 cell states
  const int rg = lane >> 4;
  const int jj = tid & 15, nbase = tid >> 4;
  const int cidx = ctile * 16 + jj;

  for (int s = 0; s < TSEQ; s++) {
    const int t = dir ? (31 - s) : s;
    // hoisted xg loads (current step, h-independent): HBM latency hides under h/MFMA
    u16 xv[16];
    {
      const u16* xcol = xg + (size_t)t * 128 * XGC + (size_t)dir * G4 + ar0 + jj;
#pragma unroll
      for (int q = 0; q < 4; q++) {
        const u16* p = xcol + (size_t)(n0 + nbase + q * 16) * XGC;
        xv[q * 4 + 0] = p[0];  xv[q * 4 + 1] = p[16];
        xv[q * 4 + 2] = p[32]; xv[q * 4 + 3] = p[48];
      }
    }
    // A fragments via MALL-coherent loads (h written by peer blocks, possibly other XCDs)
    const u16* hb = hin + (size_t)dir * NB * KPAD;
    bf16x8 areg[13][2];
#pragma unroll
    for (int k = 0; k < 13; k++)
#pragma unroll
      for (int i = 0; i < 2; i++)
        load_h_frag(&areg[k][i],
                    &hb[(size_t)(n0 + wr * 32 + i * 16 + fr) * KPAD + k * 32 + fkb]);
    asm volatile("s_waitcnt vmcnt(0)" ::: "memory");
    __builtin_amdgcn_sched_barrier(0);
    f32x4 acc[2][2] = {};
#pragma unroll
    for (int k = 0; k < 13; k++) {
      bf16x8 bf0 = *(const bf16x8*)&Bs[(wc * 32 + fr) * BPITCH + k * 32 + fkb];
      bf16x8 bf1 = *(const bf16x8*)&Bs[(wc * 32 + 16 + fr) * BPITCH + k * 32 + fkb];
      acc[0][0] = __builtin_amdgcn_mfma_f32_16x16x32_bf16(areg[k][0], bf0, acc[0][0], 0, 0, 0);
      acc[0][1] = __builtin_amdgcn_mfma_f32_16x16x32_bf16(areg[k][0], bf1, acc[0][1], 0, 0, 0);
      acc[1][0] = __builtin_amdgcn_mfma_f32_16x16x32_bf16(areg[k][1], bf0, acc[1][0], 0, 0, 0);
      acc[1][1] = __builtin_amdgcn_mfma_f32_16x16x32_bf16(areg[k][1], bf1, acc[1][1], 0, 0, 0);
    }
    // transpose gates through LDS for i/f/g/o gather
#pragma unroll
    for (int i = 0; i < 2; i++)
#pragma unroll
      for (int j = 0; j < 2; j++)
#pragma unroll
        for (int r = 0; r < 4; r++)
          gs[(wr * 32 + i * 16 + rg * 4 + r) * 68 + wc * 32 + j * 16 + fr] = acc[i][j][r];
    __syncthreads();
    // elementwise: this thread owns col jj, rows nbase+16q (c in registers)
#pragma unroll
    for (int q = 0; q < 4; q++) {
      int nl = nbase + q * 16;
      int n = n0 + nl;
      float gi = gs[nl * 68 + jj]      + b2f(xv[q * 4 + 0]) + biasS[jj];
      float gf = gs[nl * 68 + 16 + jj] + b2f(xv[q * 4 + 1]) + biasS[16 + jj];
      float gg = gs[nl * 68 + 32 + jj] + b2f(xv[q * 4 + 2]) + biasS[32 + jj];
      float go = gs[nl * 68 + 48 + jj] + b2f(xv[q * 4 + 3]) + biasS[48 + jj];
      float c_new = sigm_(gf) * c_reg[q] + sigm_(gi) * tanh_(gg);
      float h_new = sigm_(go) * tanh_(c_new);
      c_reg[q] = c_new;
      u16 hv = f2b(h_new);
      store_h16(&hout[((size_t)dir * NB + n) * KPAD + cidx], (unsigned)hv);  // write-through
      h_cat[(size_t)(t * 128 + n) * 800 + dir * HDIM + cidx] = hv;           // cached ok
    }
    __syncthreads();   // drains vmcnt(0): all sc1 h-stores committed at MALL
    if (tid == 0) {
      __hip_atomic_fetch_add(cnt, 1u, __ATOMIC_RELAXED, __HIP_MEMORY_SCOPE_AGENT);
      unsigned target = 25u * (unsigned)(s + 1);
      while (poll_cnt(cnt) < target) __builtin_amdgcn_s_sleep(1);
    }
    __syncthreads();
    u16* tmp = (u16*)hin; hin = hout; hout = tmp;
  }
}

// ---------- a/bm projection: [4096][200] = h1 @ W1ab^T, written permuted ----------
__global__ __launch_bounds__(256) void ab_gemm(
    const u16* __restrict__ h1, const u16* __restrict__ W1ab,
    const float* __restrict__ smallf, float* __restrict__ abuf, float* __restrict__ bbuf) {
  int lane = threadIdx.x & 63, wv = threadIdx.x >> 6;
  int mt = blockIdx.y * 4 + wv;
  int nt = blockIdx.x;
  int r0 = mt * 16, c0 = nt * 16;
  f32x4 acc = {};
  int fr = lane & 15, fk8 = (lane >> 4) * 8;
  for (int k0 = 0; k0 < 800; k0 += 32) {
    bf16x8 a = *(const bf16x8*)&h1[(size_t)(r0 + fr) * 800 + k0 + fk8];
    bf16x8 b = *(const bf16x8*)&W1ab[(size_t)(c0 + fr) * 800 + k0 + fk8];
    acc = __builtin_amdgcn_mfma_f32_16x16x32_bf16(a, b, acc, 0, 0, 0);
  }
  int c = c0 + fr;
  if (c < 200) {
#pragma unroll
    for (int r = 0; r < 4; r++) {
      int row = r0 + (lane >> 4) * 4 + r;
      int t = row >> 7, n = row & 127;
      int orow = n * 32 + t;
      float v = acc[r];
      if (c < 100) abuf[(size_t)orow * 100 + c] = v;
      else         bbuf[(size_t)orow * 100 + (c - 100)] = v + smallf[c - 100];
    }
  }
}

// ---------- fused pairwise MLP ----------
__global__ __launch_bounds__(256) void pairwise(
    const float* __restrict__ abuf, const float* __restrict__ bbuf,
    const float* __restrict__ smallf, const int* __restrict__ flag,
    void* __restrict__ outp) {
  __shared__ float aS[16 * 101];
  __shared__ float bS[16 * 101];
  __shared__ float w2S[104];
  int b = blockIdx.z, i0 = blockIdx.y * 16, j0 = blockIdx.x * 16;
  int tid = threadIdx.x;
  for (int idx = tid; idx < 1600; idx += 256) {
    int r = idx / 100, h = idx - r * 100;
    aS[r * 101 + h] = abuf[((size_t)(i0 + r) * 32 + b) * 100 + h];
    bS[r * 101 + h] = bbuf[((size_t)(j0 + r) * 32 + b) * 100 + h];
  }
  if (tid < 100) w2S[tid] = smallf[100 + tid];
  __syncthreads();
  float bias2 = smallf[200];
  int di = tid >> 4, dj = tid & 15;
  const float* ar = &aS[di * 101];
  const float* br = &bS[dj * 101];
  float s = 0.0f;
#pragma unroll 4
  for (int h = 0; h < 100; h++) s += w2S[h] * tanh_(ar[h] + br[h]);
  int i = i0 + di, j = j0 + dj;
  size_t pos = ((size_t)(i * 128 + j)) * 32 + b;
  float v = s + bias2;
  if (flag[0]) ((u16*)outp)[pos] = f2b(v);
  else         ((float*)outp)[pos] = v;
}

// ---------- host ----------
extern "C" void kernel_launch(void* const* d_in, const int* in_sizes, int n_in,
                              void* d_out, int out_size, void* d_ws, size_t ws_size,
                              hipStream_t stream) {
  (void)in_sizes; (void)n_in; (void)out_size; (void)ws_size;
  const int* words = (const int*)d_in[0];
  const int* tags  = (const int*)d_in[1];
  const void* wemb = d_in[4];
  const void* temb = d_in[5];
  const void* wih[4] = {d_in[6],  d_in[10], d_in[14], d_in[18]};
  const void* whh[4] = {d_in[7],  d_in[11], d_in[15], d_in[19]};
  const void* bih[4] = {d_in[8],  d_in[12], d_in[16], d_in[20]};
  const void* bhh[4] = {d_in[9],  d_in[13], d_in[17], d_in[21]};
  const void* w1 = d_in[22];
  const void* b1 = d_in[23];
  const void* w2 = d_in[24];
  const void* b2 = d_in[25];

  char* ws = (char*)d_ws;
  size_t off = 0;
  auto alloc = [&](size_t bytes) -> void* {
    void* p = ws + off; off = (off + bytes + 255) & ~(size_t)255; return p;
  };
  int*      flag  = (int*)     alloc(256);
  u16*      hstate= (u16*)     alloc((size_t)2 * 2 * NB * KPAD * 2);  // ping+pong, 416 KB
  unsigned* bar   = (unsigned*)alloc(256);                            // 4 counters, 32B apart
  float*    smallf= (float*)   alloc(201 * 4);
  float*    abuf  = (float*)   alloc((size_t)TOK * 100 * 4);
  float*    bbuf  = (float*)   alloc((size_t)TOK * 100 * 4);
  u16*      hcat0 = (u16*)     alloc((size_t)TOK * 800 * 2);
  u16*      hcat1 = (u16*)     alloc((size_t)TOK * 800 * 2);
  u16*      XP    = (u16*)     alloc((size_t)TOK * KPAD * 2);
  u16*      xg    = (u16*)     alloc((size_t)TOK * XGC * 2);          // 26.2 MB
  u16*      W0a   = (u16*)     alloc((size_t)2 * G4 * KPAD * 2);
  u16*      W1a   = (u16*)     alloc((size_t)2 * G4 * 800 * 2);
  u16*      WhhA  = (u16*)     alloc((size_t)4 * G4 * KPAD * 2);
  float*    biasA = (float*)   alloc((size_t)4 * G4 * 4);
  u16*      W1ab  = (u16*)     alloc((size_t)208 * 800 * 2);

  const size_t stateBytes = (size_t)2 * 2 * NB * KPAD * 2;  // 425984, multiple of 256
  u16* h0 = hstate;
  u16* h1 = hstate + (size_t)2 * NB * KPAD;

  sniff_kernel<<<1, 256, 0, stream>>>(wemb, flag);
  hipMemsetAsync(XP, 0, (size_t)TOK * KPAD * 2, stream);     // zero K-pad cols
  prep_kernel<<<26276, 256, 0, stream>>>(
      wih[0], wih[1], wih[2], wih[3], whh[0], whh[1], whh[2], whh[3],
      bih[0], bih[1], bih[2], bih[3], bhh[0], bhh[1], bhh[2], bhh[3],
      w1, b1, w2, b2, flag, W0a, W1a, WhhA, biasA, W1ab, smallf);
  embed_kernel<<<6400, 256, 0, stream>>>(words, tags, wemb, temb, flag, XP);

  // layer 0: xg = XP @ W0a^T ; persistent recurrence
  gemm_bt<<<dim3(25, 32), 256, 0, stream>>>(XP, W0a, xg, TOK, XGC, KPAD);
  hipMemsetAsync(hstate, 0, stateBytes + 256, stream);       // h ping/pong + barrier counters
  lstm_persist<<<dim3(25, 2, 2), 256, 0, stream>>>(
      xg, WhhA, biasA, h0, h1, hcat0, bar);

  // layer 1: xg = hcat0 @ W1a^T ; persistent recurrence
  gemm_bt<<<dim3(25, 32), 256, 0, stream>>>(hcat0, W1a, xg, TOK, XGC, 800);
  hipMemsetAsync(hstate, 0, stateBytes + 256, stream);
  lstm_persist<<<dim3(25, 2, 2), 256, 0, stream>>>(
      xg, WhhA + (size_t)2 * G4 * KPAD, biasA + 2 * G4, h0, h1, hcat1, bar);

  ab_gemm<<<dim3(13, 64), 256, 0, stream>>>(hcat1, W1ab, smallf, abuf, bbuf);
  pairwise<<<dim3(8, 8, 32), 256, 0, stream>>>(abuf, bbuf, smallf, flag, d_out);
}

// Round 6
// 482.813 us; speedup vs baseline: 2.5896x; 1.2180x over previous
//
#include <hip/hip_runtime.h>

typedef unsigned short u16;
typedef __attribute__((ext_vector_type(8))) short bf16x8;   // 8 bf16 = 4 VGPRs (MFMA A/B frag)
typedef __attribute__((ext_vector_type(4))) float f32x4;    // MFMA C/D frag

// ---------- constants ----------
#define TSEQ 32      // LSTM time steps (reshape bug: seq runs over B)
#define NB   128     // LSTM batch
#define HDIM 400
#define KPAD 416     // 400 padded to 13*32 for MFMA K
#define G4   1600    // 4*H
#define TOK  4096    // 32*128 tokens
#define XGC  3200    // both dirs' gate cols
#define BPITCH 420   // LDS Whh pitch (shorts)

__device__ __forceinline__ float b2f(u16 u) {
  union { unsigned int i; float f; } v; v.i = ((unsigned int)u) << 16; return v.f;
}
__device__ __forceinline__ u16 f2b(float f) {
  union { float fl; unsigned int i; } v; v.fl = f;
  unsigned int r = v.i + 0x7fffu + ((v.i >> 16) & 1u);   // RNE
  return (u16)(r >> 16);
}
__device__ __forceinline__ float loadf(const void* p, long long i, int isbf) {
  return isbf ? b2f(((const u16*)p)[i]) : ((const float*)p)[i];
}
__device__ __forceinline__ u16 loadb(const void* p, long long i, int isbf) {
  return isbf ? ((const u16*)p)[i] : f2b(((const float*)p)[i]);
}
__device__ __forceinline__ float sigm_(float x) { return 1.0f / (1.0f + __expf(-x)); }
__device__ __forceinline__ float tanh_(float x) {
  float e = __expf(2.0f * x);
  return 1.0f - 2.0f / (e + 1.0f);   // exact limits at +-inf, no NaN
}

// MALL-coherent (cross-XCD) primitives: sc0 sc1 = bypass/write-through L2. No fences.
__device__ __forceinline__ void load_h_frag(bf16x8* dst, const u16* p) {
  asm volatile("global_load_dwordx4 %0, %1, off sc0 sc1" : "=v"(*dst) : "v"(p));
}
__device__ __forceinline__ void store_h16(u16* p, unsigned v) {
  asm volatile("global_store_short %0, %1, off sc0 sc1" :: "v"(p), "v"(v) : "memory");
}
__device__ __forceinline__ void store_flag(unsigned* p, unsigned v) {
  asm volatile("global_store_dword %0, %1, off sc0 sc1" :: "v"(p), "v"(v) : "memory");
}
__device__ __forceinline__ unsigned poll_cnt(const unsigned* p) {
  unsigned v;
  asm volatile("global_load_dword %0, %1, off sc0 sc1\n\ts_waitcnt vmcnt(0)"
               : "=v"(v) : "v"(p) : "memory");
  return v;
}

// ---------- input dtype sniffer ----------
__global__ __launch_bounds__(256) void sniff_kernel(const void* wemb, int* flag) {
  __shared__ int cf, cb;
  if (threadIdx.x == 0) { cf = 0; cb = 0; }
  __syncthreads();
  int okf = 0, okb = 0;
  for (int i = threadIdx.x; i < 8192; i += 256) {
    float f = ((const float*)wemb)[i];
    float af = fabsf(f);
    if (af > 1e-12f && af < 8.0f) okf++;
    u16 ub = ((const u16*)wemb)[i];
    float fb = b2f(ub); float ab = fabsf(fb);
    if (ub == 0 || (ab > 1e-12f && ab < 8.0f)) okb++;
  }
  atomicAdd(&cf, okf);
  atomicAdd(&cb, okb);
  __syncthreads();
  if (threadIdx.x == 0) flag[0] = (cb > cf) ? 1 : 0;
}

// ---------- embedding + faithful reshape ----------
// XP[t*128+n, d] = concat(word_emb, tag_emb)[flat row n*32+t]  (the view(L,B,-1) bug)
// XP pad cols [400,416) are never written: they hold finite 0xAA poison which is
// multiplied by ZERO weight cols (prep zero-pads W0a) -> contributes exactly 0.
__global__ __launch_bounds__(256) void embed_kernel(
    const int* __restrict__ words, const int* __restrict__ tags,
    const void* __restrict__ wemb, const void* __restrict__ temb,
    const int* __restrict__ flag, u16* __restrict__ XP) {
  const int isbf = flag[0];
  int idx = blockIdx.x * 256 + threadIdx.x;      // 4096*400
  if (idx >= TOK * 400) return;
  int r = idx / 400, d = idx - r * 400;
  int t = r >> 7, n = r & 127;
  int m = n * 32 + t;                            // flat row of embeds (B,L,400)
  int b = m >> 7, l = m & 127;
  u16 v;
  if (d < 300) v = loadb(wemb, (long long)words[b * 128 + l] * 300 + d, isbf);
  else         v = loadb(temb, (long long)tags[b * 128 + l] * 100 + (d - 300), isbf);
  XP[(size_t)r * KPAD + d] = v;
}

// ---------- weight pre-arrangement ----------
// arranged gate row: ar = ctile*64 + type*16 + j  <->  orig row = type*400 + ctile*16 + j
__global__ __launch_bounds__(256) void prep_kernel(
    const void* wih0, const void* wih1, const void* wih2, const void* wih3,
    const void* whhA0, const void* whhA1, const void* whhA2, const void* whhA3,
    const void* bih0, const void* bih1, const void* bih2, const void* bih3,
    const void* bhh0, const void* bhh1, const void* bhh2, const void* bhh3,
    const void* w1, const void* b1, const void* w2, const void* b2,
    const int* __restrict__ flag,
    u16* __restrict__ W0a, u16* __restrict__ W1a, u16* __restrict__ WhhA,
    float* __restrict__ biasA, u16* __restrict__ W1ab, float* __restrict__ smallf) {
  const int isbf = flag[0];
  long long idx = (long long)blockIdx.x * 256 + threadIdx.x;
  const void* wihs[4] = {wih0, wih1, wih2, wih3};
  const void* whhs[4] = {whhA0, whhA1, whhA2, whhA3};
  const void* bihs[4] = {bih0, bih1, bih2, bih3};
  const void* bhhs[4] = {bhh0, bhh1, bhh2, bhh3};
  const long long c1 = 1331200LL, c2 = 3891200LL, c3 = 6553600LL, c4 = 6560000LL,
                  c5 = 6726400LL, c6 = 6726601LL;
  if (idx < c1) {                       // W0a: [2][1600][416]
    int j = (int)idx; int row = j / KPAD; int k = j - row * KPAD;
    int dir = row / G4; int ar = row - dir * G4;
    int ct = ar >> 6, rem = ar & 63, ty = rem >> 4, jj = rem & 15;
    int srow = ty * 400 + ct * 16 + jj;
    W0a[j] = (k < 400) ? loadb(wihs[dir], (long long)srow * 400 + k, isbf) : (u16)0;
  } else if (idx < c2) {                // W1a: [2][1600][800]
    int j = (int)(idx - c1); int row = j / 800; int k = j - row * 800;
    int dir = row / G4; int ar = row - dir * G4;
    int ct = ar >> 6, rem = ar & 63, ty = rem >> 4, jj = rem & 15;
    int srow = ty * 400 + ct * 16 + jj;
    W1a[j] = loadb(wihs[2 + dir], (long long)srow * 800 + k, isbf);
  } else if (idx < c3) {                // WhhA: [4][1600][416]
    int j = (int)(idx - c2); int row = j / KPAD; int k = j - row * KPAD;
    int dl = row / G4; int ar = row - dl * G4;
    int ct = ar >> 6, rem = ar & 63, ty = rem >> 4, jj = rem & 15;
    int srow = ty * 400 + ct * 16 + jj;
    WhhA[j] = (k < 400) ? loadb(whhs[dl], (long long)srow * 400 + k, isbf) : (u16)0;
  } else if (idx < c4) {                // biasA: [4][1600]
    int j = (int)(idx - c3); int dl = j / G4; int ar = j - dl * G4;
    int ct = ar >> 6, rem = ar & 63, ty = rem >> 4, jj = rem & 15;
    int srow = ty * 400 + ct * 16 + jj;
    biasA[j] = loadf(bihs[dl], srow, isbf) + loadf(bhhs[dl], srow, isbf);
  } else if (idx < c5) {                // W1ab: [208][800]
    int j = (int)(idx - c4); int row = j / 800; int k = j - row * 800;
    u16 v = 0;
    if (row < 100)      v = loadb(w1, (long long)row * 1600 + k, isbf);
    else if (row < 200) v = loadb(w1, (long long)(row - 100) * 1600 + 800 + k, isbf);
    W1ab[j] = v;
  } else if (idx < c6) {                // smallf: b1(100), w2(100), b2(1)
    int j = (int)(idx - c5);
    if (j < 100)       smallf[j] = loadf(b1, j, isbf);
    else if (j < 200)  smallf[j] = loadf(w2, j - 100, isbf);
    else               smallf[200] = loadf(b2, 0, isbf);
  }
}

// ---------- 128x128-tile bf16 GEMM: C[M][N] = A[M][K] @ B[N][K]^T (bf16 out) ----------
__global__ __launch_bounds__(256) void gemm_bt(
    const u16* __restrict__ A, const u16* __restrict__ B, u16* __restrict__ C,
    int M, int N, int K) {
  __shared__ u16 As[128 * 40];      // pitch 40 shorts = 80B
  __shared__ u16 Bs[128 * 40];
  int tid = threadIdx.x;
  int wave = tid >> 6, lane = tid & 63;
  int m0 = blockIdx.y << 7, n0 = blockIdx.x << 7;
  int wr = wave >> 1, wc = wave & 1;
  int arow = tid >> 2, aseg = tid & 3;
  const size_t aoff0 = (size_t)(m0 + arow) * K + aseg * 8;
  const size_t aoff1 = (size_t)(m0 + 64 + arow) * K + aseg * 8;
  const size_t boff0 = (size_t)(n0 + arow) * K + aseg * 8;
  const size_t boff1 = (size_t)(n0 + 64 + arow) * K + aseg * 8;
  float4 ra0 = *(const float4*)&A[aoff0];
  float4 ra1 = *(const float4*)&A[aoff1];
  float4 rb0 = *(const float4*)&B[boff0];
  float4 rb1 = *(const float4*)&B[boff1];
  f32x4 acc[4][4] = {};
  int fr = lane & 15, fkb = (lane >> 4) * 8;
  for (int k0 = 32;; k0 += 32) {
    __syncthreads();
    *(float4*)&As[arow * 40 + aseg * 8] = ra0;
    *(float4*)&As[(64 + arow) * 40 + aseg * 8] = ra1;
    *(float4*)&Bs[arow * 40 + aseg * 8] = rb0;
    *(float4*)&Bs[(64 + arow) * 40 + aseg * 8] = rb1;
    bool more = k0 < K;
    if (more) {
      ra0 = *(const float4*)&A[aoff0 + k0];
      ra1 = *(const float4*)&A[aoff1 + k0];
      rb0 = *(const float4*)&B[boff0 + k0];
      rb1 = *(const float4*)&B[boff1 + k0];
    }
    __syncthreads();
    bf16x8 af[4], bf[4];
#pragma unroll
    for (int i = 0; i < 4; i++) af[i] = *(const bf16x8*)&As[(wr * 64 + i * 16 + fr) * 40 + fkb];
#pragma unroll
    for (int i = 0; i < 4; i++) bf[i] = *(const bf16x8*)&Bs[(wc * 64 + i * 16 + fr) * 40 + fkb];
#pragma unroll
    for (int i = 0; i < 4; i++)
#pragma unroll
      for (int j = 0; j < 4; j++)
        acc[i][j] = __builtin_amdgcn_mfma_f32_16x16x32_bf16(af[i], bf[j], acc[i][j], 0, 0, 0);
    if (!more) break;
  }
  int rg = lane >> 4;
#pragma unroll
  for (int i = 0; i < 4; i++)
#pragma unroll
    for (int j = 0; j < 4; j++)
#pragma unroll
      for (int r = 0; r < 4; r++) {
        int row = m0 + wr * 64 + i * 16 + rg * 4 + r;
        int col = n0 + wc * 64 + j * 16 + fr;
        C[(size_t)row * N + col] = f2b(acc[i][j][r]);
      }
}

// ---------- persistent LSTM layer: 1 launch, 32 steps, grid(25,2,2)=100 blocks ----------
// Block (ctile, ntile, dir). Whh slice LDS-resident; h via MALL (sc0 sc1); c in regs.
// Barrier = 25-flag vector: producer stores flag[ctile]=s+1 after h drain; 25 consumer
// threads poll in parallel. Step 0 skips h loads (h0 = 0) -> hstate needs no zeroing.
__global__ __launch_bounds__(256) void lstm_persist(
    const u16* __restrict__ xg,      // [4096][3200] precomputed x-part (no bias)
    const u16* __restrict__ Whh,     // [2][1600][416] arranged (this layer)
    const float* __restrict__ bias,  // [2][1600] arranged (this layer)
    u16* __restrict__ hA,            // [2][128][416] ping (pad cols: finite poison x 0-weights)
    u16* __restrict__ hB,            // [2][128][416] pong
    u16* __restrict__ h_cat,         // [4096][800]
    unsigned* __restrict__ flags) {  // [4 groups][32] zeroed
  __shared__ u16 Bs[64 * BPITCH];    // 53760 B
  __shared__ float gs[64 * 68];      // 17408 B
  __shared__ float biasS[64];
  const int ctile = blockIdx.x, ntile = blockIdx.y, dir = blockIdx.z;
  const int n0 = ntile * 64, ar0 = ctile * 64;
  const int tid = threadIdx.x, lane = tid & 63, wave = tid >> 6;
  const int wr = wave >> 1, wc = wave & 1;
  const int fr = lane & 15, fkb = (lane >> 4) * 8;
  unsigned* flagbase = flags + (dir * 2 + ntile) * 32;

  // stage Whh slice (64 rows x 416) into LDS, coalesced float4
  const u16* wbase = Whh + ((size_t)dir * G4 + ar0) * KPAD;
  for (int idx = tid; idx < 64 * 52; idx += 256) {
    int r = idx / 52, kk = (idx - r * 52) * 8;
    *(float4*)&Bs[r * BPITCH + kk] = *(const float4*)&wbase[(size_t)r * KPAD + kk];
  }
  if (tid < 64) biasS[tid] = bias[dir * G4 + ar0 + tid];
  __syncthreads();

  const u16* hin = hA;
  u16* hout = hB;
  float c_reg[4] = {0.f, 0.f, 0.f, 0.f};
  const int rg = lane >> 4;
  const int jj = tid & 15, nbase = tid >> 4;
  const int cidx = ctile * 16 + jj;

  // prefetch xv for step 0
  u16 xv[16], xvn[16];
  {
    const int t0 = dir ? 31 : 0;
    const u16* xcol = xg + (size_t)t0 * 128 * XGC + (size_t)dir * G4 + ar0 + jj;
#pragma unroll
    for (int q = 0; q < 4; q++) {
      const u16* p = xcol + (size_t)(n0 + nbase + q * 16) * XGC;
      xv[q * 4 + 0] = p[0];  xv[q * 4 + 1] = p[16];
      xv[q * 4 + 2] = p[32]; xv[q * 4 + 3] = p[48];
    }
  }

  for (int s = 0; s < TSEQ; s++) {
    const int t = dir ? (31 - s) : s;
    f32x4 acc[2][2];
    if (s == 0) {
#pragma unroll
      for (int i = 0; i < 2; i++)
#pragma unroll
        for (int j = 0; j < 2; j++) acc[i][j] = (f32x4){0.f, 0.f, 0.f, 0.f};
    } else {
      // A fragments via MALL-coherent loads (h written by peers, possibly other XCDs)
      const u16* hb = hin + (size_t)dir * NB * KPAD;
      bf16x8 areg[13][2];
#pragma unroll
      for (int k = 0; k < 13; k++)
#pragma unroll
        for (int i = 0; i < 2; i++)
          load_h_frag(&areg[k][i],
                      &hb[(size_t)(n0 + wr * 32 + i * 16 + fr) * KPAD + k * 32 + fkb]);
      asm volatile("s_waitcnt vmcnt(0)" ::: "memory");
      __builtin_amdgcn_sched_barrier(0);
#pragma unroll
      for (int i = 0; i < 2; i++)
#pragma unroll
        for (int j = 0; j < 2; j++) acc[i][j] = (f32x4){0.f, 0.f, 0.f, 0.f};
#pragma unroll
      for (int k = 0; k < 13; k++) {
        bf16x8 bf0 = *(const bf16x8*)&Bs[(wc * 32 + fr) * BPITCH + k * 32 + fkb];
        bf16x8 bf1 = *(const bf16x8*)&Bs[(wc * 32 + 16 + fr) * BPITCH + k * 32 + fkb];
        acc[0][0] = __builtin_amdgcn_mfma_f32_16x16x32_bf16(areg[k][0], bf0, acc[0][0], 0, 0, 0);
        acc[0][1] = __builtin_amdgcn_mfma_f32_16x16x32_bf16(areg[k][0], bf1, acc[0][1], 0, 0, 0);
        acc[1][0] = __builtin_amdgcn_mfma_f32_16x16x32_bf16(areg[k][1], bf0, acc[1][0], 0, 0, 0);
        acc[1][1] = __builtin_amdgcn_mfma_f32_16x16x32_bf16(areg[k][1], bf1, acc[1][1], 0, 0, 0);
      }
    }
    // transpose gates through LDS for i/f/g/o gather
#pragma unroll
    for (int i = 0; i < 2; i++)
#pragma unroll
      for (int j = 0; j < 2; j++)
#pragma unroll
        for (int r = 0; r < 4; r++)
          gs[(wr * 32 + i * 16 + rg * 4 + r) * 68 + wc * 32 + j * 16 + fr] = acc[i][j][r];
    __syncthreads();
    // elementwise: this thread owns col jj, rows nbase+16q (c in registers)
    u16 hvals[4];
#pragma unroll
    for (int q = 0; q < 4; q++) {
      int nl = nbase + q * 16;
      int n = n0 + nl;
      float gi = gs[nl * 68 + jj]      + b2f(xv[q * 4 + 0]) + biasS[jj];
      float gf = gs[nl * 68 + 16 + jj] + b2f(xv[q * 4 + 1]) + biasS[16 + jj];
      float gg = gs[nl * 68 + 32 + jj] + b2f(xv[q * 4 + 2]) + biasS[32 + jj];
      float go = gs[nl * 68 + 48 + jj] + b2f(xv[q * 4 + 3]) + biasS[48 + jj];
      float c_new = sigm_(gf) * c_reg[q] + sigm_(gi) * tanh_(gg);
      float h_new = sigm_(go) * tanh_(c_new);
      c_reg[q] = c_new;
      hvals[q] = f2b(h_new);
      store_h16(&hout[((size_t)dir * NB + n) * KPAD + cidx], (unsigned)hvals[q]);
    }
    // drain h stores (all threads), then signal
    asm volatile("s_waitcnt vmcnt(0)" ::: "memory");
    __syncthreads();
    if (tid == 0) store_flag(&flagbase[ctile], (unsigned)(s + 1));
    // non-critical stores + next-step xg prefetch overlap the barrier wait
#pragma unroll
    for (int q = 0; q < 4; q++)
      h_cat[(size_t)(t * 128 + n0 + nbase + q * 16) * 800 + dir * HDIM + cidx] = hvals[q];
    {
      const int sn = (s < 31) ? (s + 1) : 31;
      const int tn = dir ? (31 - sn) : sn;
      const u16* xcol = xg + (size_t)tn * 128 * XGC + (size_t)dir * G4 + ar0 + jj;
#pragma unroll
      for (int q = 0; q < 4; q++) {
        const u16* p = xcol + (size_t)(n0 + nbase + q * 16) * XGC;
        xvn[q * 4 + 0] = p[0];  xvn[q * 4 + 1] = p[16];
        xvn[q * 4 + 2] = p[32]; xvn[q * 4 + 3] = p[48];
      }
    }
    if (tid < 25) {
      const unsigned tgt = (unsigned)(s + 1);
      while (poll_cnt(&flagbase[tid]) < tgt) __builtin_amdgcn_s_sleep(2);
    }
    __syncthreads();
    u16* tmp = (u16*)hin; hin = hout; hout = tmp;
#pragma unroll
    for (int z = 0; z < 16; z++) xv[z] = xvn[z];
  }
}

// ---------- a/bm projection: [4096][200] = h1 @ W1ab^T, written permuted ----------
__global__ __launch_bounds__(256) void ab_gemm(
    const u16* __restrict__ h1, const u16* __restrict__ W1ab,
    const float* __restrict__ smallf, float* __restrict__ abuf, float* __restrict__ bbuf) {
  int lane = threadIdx.x & 63, wv = threadIdx.x >> 6;
  int mt = blockIdx.y * 4 + wv;
  int nt = blockIdx.x;
  int r0 = mt * 16, c0 = nt * 16;
  f32x4 acc = {};
  int fr = lane & 15, fk8 = (lane >> 4) * 8;
  for (int k0 = 0; k0 < 800; k0 += 32) {
    bf16x8 a = *(const bf16x8*)&h1[(size_t)(r0 + fr) * 800 + k0 + fk8];
    bf16x8 b = *(const bf16x8*)&W1ab[(size_t)(c0 + fr) * 800 + k0 + fk8];
    acc = __builtin_amdgcn_mfma_f32_16x16x32_bf16(a, b, acc, 0, 0, 0);
  }
  int c = c0 + fr;
  if (c < 200) {
#pragma unroll
    for (int r = 0; r < 4; r++) {
      int row = r0 + (lane >> 4) * 4 + r;
      int t = row >> 7, n = row & 127;
      int orow = n * 32 + t;
      float v = acc[r];
      if (c < 100) abuf[(size_t)orow * 100 + c] = v;
      else         bbuf[(size_t)orow * 100 + (c - 100)] = v + smallf[c - 100];
    }
  }
}

// ---------- fused pairwise MLP ----------
__global__ __launch_bounds__(256) void pairwise(
    const float* __restrict__ abuf, const float* __restrict__ bbuf,
    const float* __restrict__ smallf, const int* __restrict__ flag,
    void* __restrict__ outp) {
  __shared__ float aS[16 * 101];
  __shared__ float bS[16 * 101];
  __shared__ float w2S[104];
  int b = blockIdx.z, i0 = blockIdx.y * 16, j0 = blockIdx.x * 16;
  int tid = threadIdx.x;
  for (int idx = tid; idx < 1600; idx += 256) {
    int r = idx / 100, h = idx - r * 100;
    aS[r * 101 + h] = abuf[((size_t)(i0 + r) * 32 + b) * 100 + h];
    bS[r * 101 + h] = bbuf[((size_t)(j0 + r) * 32 + b) * 100 + h];
  }
  if (tid < 100) w2S[tid] = smallf[100 + tid];
  __syncthreads();
  float bias2 = smallf[200];
  int di = tid >> 4, dj = tid & 15;
  const float* ar = &aS[di * 101];
  const float* br = &bS[dj * 101];
  float s = 0.0f;
#pragma unroll 4
  for (int h = 0; h < 100; h++) s += w2S[h] * tanh_(ar[h] + br[h]);
  int i = i0 + di, j = j0 + dj;
  size_t pos = ((size_t)(i * 128 + j)) * 32 + b;
  float v = s + bias2;
  if (flag[0]) ((u16*)outp)[pos] = f2b(v);
  else         ((float*)outp)[pos] = v;
}

// ---------- host ----------
extern "C" void kernel_launch(void* const* d_in, const int* in_sizes, int n_in,
                              void* d_out, int out_size, void* d_ws, size_t ws_size,
                              hipStream_t stream) {
  (void)in_sizes; (void)n_in; (void)out_size; (void)ws_size;
  const int* words = (const int*)d_in[0];
  const int* tags  = (const int*)d_in[1];
  const void* wemb = d_in[4];
  const void* temb = d_in[5];
  const void* wih[4] = {d_in[6],  d_in[10], d_in[14], d_in[18]};
  const void* whh[4] = {d_in[7],  d_in[11], d_in[15], d_in[19]};
  const void* bih[4] = {d_in[8],  d_in[12], d_in[16], d_in[20]};
  const void* bhh[4] = {d_in[9],  d_in[13], d_in[17], d_in[21]};
  const void* w1 = d_in[22];
  const void* b1 = d_in[23];
  const void* w2 = d_in[24];
  const void* b2 = d_in[25];

  char* ws = (char*)d_ws;
  size_t off = 0;
  auto alloc = [&](size_t bytes) -> void* {
    void* p = ws + off; off = (off + bytes + 255) & ~(size_t)255; return p;
  };
  int*      flag  = (int*)     alloc(256);
  u16*      hstate= (u16*)     alloc((size_t)2 * 2 * NB * KPAD * 2);  // ping+pong (never memset)
  unsigned* flags = (unsigned*)alloc(1024);                           // 2 layers x 4 groups x 32
  float*    smallf= (float*)   alloc(201 * 4);
  float*    abuf  = (float*)   alloc((size_t)TOK * 100 * 4);
  float*    bbuf  = (float*)   alloc((size_t)TOK * 100 * 4);
  u16*      hcat0 = (u16*)     alloc((size_t)TOK * 800 * 2);
  u16*      hcat1 = (u16*)     alloc((size_t)TOK * 800 * 2);
  u16*      XP    = (u16*)     alloc((size_t)TOK * KPAD * 2);
  u16*      xg    = (u16*)     alloc((size_t)TOK * XGC * 2);          // 26.2 MB
  u16*      W0a   = (u16*)     alloc((size_t)2 * G4 * KPAD * 2);
  u16*      W1a   = (u16*)     alloc((size_t)2 * G4 * 800 * 2);
  u16*      WhhA  = (u16*)     alloc((size_t)4 * G4 * KPAD * 2);
  float*    biasA = (float*)   alloc((size_t)4 * G4 * 4);
  u16*      W1ab  = (u16*)     alloc((size_t)208 * 800 * 2);

  u16* h0 = hstate;
  u16* h1 = hstate + (size_t)2 * NB * KPAD;

  sniff_kernel<<<1, 256, 0, stream>>>(wemb, flag);
  hipMemsetAsync(flags, 0, 1024, stream);                    // only required memset
  prep_kernel<<<26276, 256, 0, stream>>>(
      wih[0], wih[1], wih[2], wih[3], whh[0], whh[1], whh[2], whh[3],
      bih[0], bih[1], bih[2], bih[3], bhh[0], bhh[1], bhh[2], bhh[3],
      w1, b1, w2, b2, flag, W0a, W1a, WhhA, biasA, W1ab, smallf);
  embed_kernel<<<6400, 256, 0, stream>>>(words, tags, wemb, temb, flag, XP);

  // layer 0: xg = XP @ W0a^T ; persistent recurrence
  gemm_bt<<<dim3(25, 32), 256, 0, stream>>>(XP, W0a, xg, TOK, XGC, KPAD);
  lstm_persist<<<dim3(25, 2, 2), 256, 0, stream>>>(
      xg, WhhA, biasA, h0, h1, hcat0, flags);

  // layer 1: xg = hcat0 @ W1a^T ; persistent recurrence
  gemm_bt<<<dim3(25, 32), 256, 0, stream>>>(hcat0, W1a, xg, TOK, XGC, 800);
  lstm_persist<<<dim3(25, 2, 2), 256, 0, stream>>>(
      xg, WhhA + (size_t)2 * G4 * KPAD, biasA + 2 * G4, h0, h1, hcat1, flags + 128);

  ab_gemm<<<dim3(13, 64), 256, 0, stream>>>(hcat1, W1ab, smallf, abuf, bbuf);
  pairwise<<<dim3(8, 8, 32), 256, 0, stream>>>(abuf, bbuf, smallf, flag, d_out);
}